// Round 1
// baseline (2931.324 us; speedup 1.0000x reference)
//
#include <hip/hip_runtime.h>
#include <hip/hip_bf16.h>

#define NNODES 50000
#define IN_DIM 256
#define OUT_DIM 128
#define SCALE 1.8f
#define ALPHA 0.15f

// ---------------- degree / dinv ----------------

__global__ void deg_init_kernel(float* __restrict__ deg) {
    int i = blockIdx.x * blockDim.x + threadIdx.x;
    if (i < NNODES) deg[i] = 1.0f;  // self-loop
}

__global__ void deg_scatter_kernel(const int* __restrict__ col, float* __restrict__ deg, int E) {
    int e = blockIdx.x * blockDim.x + threadIdx.x;
    if (e < E) atomicAdd(&deg[col[e]], 1.0f);
}

__global__ void dinv_kernel(float* __restrict__ deg) {
    int i = blockIdx.x * blockDim.x + threadIdx.x;
    if (i < NNODES) deg[i] = rsqrtf(deg[i]);  // deg >= 1 always (self-loop)
}

// ---------------- GEMM + bias + L2-normalize ----------------
// one block (128 threads) per row; x-row in LDS; thread t computes column t.

__global__ void __launch_bounds__(128) gemm_norm_kernel(
        const float* __restrict__ x, const float* __restrict__ W,
        const float* __restrict__ b, float* __restrict__ hn) {
    __shared__ float xs[IN_DIM];
    __shared__ float red[OUT_DIM];
    int row = blockIdx.x;
    int t = threadIdx.x;

    xs[t]       = x[(size_t)row * IN_DIM + t];
    xs[t + 128] = x[(size_t)row * IN_DIM + t + 128];
    __syncthreads();

    const float* Wr = W + (size_t)t * IN_DIM;
    float acc = b[t];
    #pragma unroll 8
    for (int k = 0; k < IN_DIM; ++k) acc += xs[k] * Wr[k];

    red[t] = acc * acc;
    __syncthreads();
    for (int s = 64; s > 0; s >>= 1) {
        if (t < s) red[t] += red[t + s];
        __syncthreads();
    }
    float nrm = sqrtf(red[0]);
    float scl = SCALE / fmaxf(nrm, 1e-12f);
    hn[(size_t)row * OUT_DIM + t] = acc * scl;
}

// ---------------- propagation ----------------
// init: agg[i][d] = dinv[i]^2 * z[i][d]   (self-loop term, also zero-inits buffer)

__global__ void selfloop_init_kernel(const float* __restrict__ dinv,
                                     const float* __restrict__ z,
                                     float* __restrict__ agg) {
    int i = blockIdx.x * blockDim.x + threadIdx.x;
    if (i >= NNODES * OUT_DIM) return;
    int node = i >> 7;  // /128
    float d = dinv[node];
    agg[i] = d * d * z[i];
}

// scatter: 32 lanes per edge, float4 gather + 4 atomic adds each

__global__ void scatter_kernel(const int* __restrict__ row, const int* __restrict__ col,
                               const float* __restrict__ dinv,
                               const float* __restrict__ z, float* __restrict__ agg, int E) {
    int idx = blockIdx.x * blockDim.x + threadIdx.x;
    int e = idx >> 5;
    int lane = idx & 31;
    if (e >= E) return;
    int r = row[e];
    int c = col[e];
    float w = dinv[r] * dinv[c];
    const float4* zr = (const float4*)(z + (size_t)r * OUT_DIM);
    float4 v = zr[lane];
    float* ap = agg + (size_t)c * OUT_DIM + lane * 4;
    atomicAdd(ap + 0, w * v.x);
    atomicAdd(ap + 1, w * v.y);
    atomicAdd(ap + 2, w * v.z);
    atomicAdd(ap + 3, w * v.w);
}

// combine: agg = (1-alpha)*agg + alpha*hn  (in place)

__global__ void combine_kernel(float* __restrict__ agg, const float* __restrict__ hn) {
    int i = blockIdx.x * blockDim.x + threadIdx.x;
    if (i >= NNODES * OUT_DIM) return;
    agg[i] = (1.0f - ALPHA) * agg[i] + ALPHA * hn[i];
}

extern "C" void kernel_launch(void* const* d_in, const int* in_sizes, int n_in,
                              void* d_out, int out_size, void* d_ws, size_t ws_size,
                              hipStream_t stream) {
    const float* x  = (const float*)d_in[0];
    const int*   ei = (const int*)d_in[1];
    const float* W  = (const float*)d_in[2];
    const float* b  = (const float*)d_in[3];
    float* out = (float*)d_out;

    int E = in_sizes[1] / 2;
    const int* row = ei;       // sources
    const int* col = ei + E;   // targets

    float* dinv = (float*)d_ws;
    float* hn   = dinv + 50048;                       // [N,128] normalized features
    float* aggA = hn + (size_t)NNODES * OUT_DIM;      // [N,128] iter-1 buffer

    const int total = NNODES * OUT_DIM;

    // degrees -> dinv
    deg_init_kernel<<<(NNODES + 255) / 256, 256, 0, stream>>>(dinv);
    deg_scatter_kernel<<<(E + 255) / 256, 256, 0, stream>>>(col, dinv, E);
    dinv_kernel<<<(NNODES + 255) / 256, 256, 0, stream>>>(dinv);

    // h = normalize(x @ W.T + b) * SCALE
    gemm_norm_kernel<<<NNODES, 128, 0, stream>>>(x, W, b, hn);

    // iteration 1: aggA = A_hat @ hn ; zA = 0.85*aggA + 0.15*hn (in aggA)
    selfloop_init_kernel<<<(total + 255) / 256, 256, 0, stream>>>(dinv, hn, aggA);
    scatter_kernel<<<((size_t)E * 32 + 255) / 256, 256, 0, stream>>>(row, col, dinv, hn, aggA, E);
    combine_kernel<<<(total + 255) / 256, 256, 0, stream>>>(aggA, hn);

    // iteration 2: out = A_hat @ zA ; out = 0.85*out + 0.15*hn (in place)
    selfloop_init_kernel<<<(total + 255) / 256, 256, 0, stream>>>(dinv, aggA, out);
    scatter_kernel<<<((size_t)E * 32 + 255) / 256, 256, 0, stream>>>(row, col, dinv, aggA, out, E);
    combine_kernel<<<(total + 255) / 256, 256, 0, stream>>>(out, hn);
}

// Round 2
// 379.966 us; speedup vs baseline: 7.7147x; 7.7147x over previous
//
#include <hip/hip_runtime.h>
#include <hip/hip_bf16.h>

#define NNODES 50000
#define IN_DIM 256
#define OUT_DIM 128
#define SCALE 1.8f
#define ALPHA 0.15f
#define NB_SCAN 196  // ceil(50000/256)

// ---------------- degree / dinv / cnt ----------------

__global__ void deg_init_kernel(float* __restrict__ deg) {
    int i = blockIdx.x * blockDim.x + threadIdx.x;
    if (i < NNODES) deg[i] = 1.0f;  // self-loop
}

__global__ void deg_scatter_kernel(const int* __restrict__ col, float* __restrict__ deg, int E) {
    int e = blockIdx.x * blockDim.x + threadIdx.x;
    if (e < E) atomicAdd(&deg[col[e]], 1.0f);
}

// dinv = rsqrt(deg); cnt = in-degree without self-loop (exact in fp32 for small counts)
__global__ void dinv_cnt_kernel(float* __restrict__ deg, int* __restrict__ cnt) {
    int i = blockIdx.x * blockDim.x + threadIdx.x;
    if (i < NNODES) {
        float d = deg[i];
        cnt[i] = (int)d - 1;
        deg[i] = rsqrtf(d);
    }
}

// ---------------- exclusive scan (3-pass) over cnt -> off, cur ----------------

__global__ void scan_pass1(const int* __restrict__ cnt, int* __restrict__ part) {
    __shared__ int sd[256];
    int t = threadIdx.x;
    int i = blockIdx.x * 256 + t;
    sd[t] = (i < NNODES) ? cnt[i] : 0;
    __syncthreads();
    for (int s = 128; s > 0; s >>= 1) {
        if (t < s) sd[t] += sd[t + s];
        __syncthreads();
    }
    if (t == 0) part[blockIdx.x] = sd[0];
}

__global__ void scan_pass2(int* __restrict__ part) {  // in-place exclusive scan of part[NB_SCAN]
    __shared__ int s[256];
    int t = threadIdx.x;
    int v = (t < NB_SCAN) ? part[t] : 0;
    s[t] = v;
    __syncthreads();
    for (int o = 1; o < 256; o <<= 1) {
        int u = (t >= o) ? s[t - o] : 0;
        __syncthreads();
        s[t] += u;
        __syncthreads();
    }
    if (t < NB_SCAN) part[t] = (t == 0) ? 0 : s[t - 1];
}

__global__ void scan_pass3(const int* __restrict__ cnt, const int* __restrict__ part,
                           int* __restrict__ off, int* __restrict__ cur, int E) {
    __shared__ int s[256];
    int t = threadIdx.x;
    int i = blockIdx.x * 256 + t;
    int v = (i < NNODES) ? cnt[i] : 0;
    s[t] = v;
    __syncthreads();
    for (int o = 1; o < 256; o <<= 1) {
        int u = (t >= o) ? s[t - o] : 0;
        __syncthreads();
        s[t] += u;
        __syncthreads();
    }
    int excl = part[blockIdx.x] + ((t == 0) ? 0 : s[t - 1]);
    if (i < NNODES) { off[i] = excl; cur[i] = excl; }
    if (i == NNODES - 1) off[NNODES] = E;
}

__global__ void csr_fill_kernel(const int* __restrict__ row, const int* __restrict__ col,
                                int* __restrict__ cur, int* __restrict__ csr_row, int E) {
    int e = blockIdx.x * blockDim.x + threadIdx.x;
    if (e < E) {
        int c = col[e];
        int p = atomicAdd(&cur[c], 1);
        csr_row[p] = row[e];
    }
}

// ---------------- fused tiled GEMM + bias + L2-normalize ----------------
// C[50000 x 128] = X[50000 x 256] @ W^T + b, then row L2-norm * SCALE.
// BM=64, BN=128 (all cols), BK=64. 256 threads, 8 rows x 4 cols per thread.

__global__ void __launch_bounds__(256) gemm_norm_kernel(
        const float* __restrict__ x, const float* __restrict__ W,
        const float* __restrict__ b, float* __restrict__ hn) {
    __shared__ float xs[64][68];    // X tile [row][k], padded
    __shared__ float wsT[64][132];  // W tile transposed [k][col], padded

    const int t = threadIdx.x;
    const int cg = t & 31;        // col group
    const int rg = t >> 5;        // row group
    const int c0 = cg * 4;
    const int r0 = rg * 8;
    const int rowBase = blockIdx.x * 64;

    float acc[8][4];
    const float4 bv = *(const float4*)(b + c0);
    #pragma unroll
    for (int i = 0; i < 8; ++i) {
        acc[i][0] = bv.x; acc[i][1] = bv.y; acc[i][2] = bv.z; acc[i][3] = bv.w;
    }

    const int lr = t >> 4;        // 0..15
    const int lk = (t & 15) * 4;  // 0..60 step 4

    for (int kt = 0; kt < 4; ++kt) {
        const int kBase = kt * 64;
        // load X tile: 64 rows x 64 k, float4 per thread x 4 iters
        #pragma unroll
        for (int i = 0; i < 4; ++i) {
            int r = i * 16 + lr;
            int grow = rowBase + r;
            float4 v = make_float4(0.f, 0.f, 0.f, 0.f);
            if (grow < NNODES) v = *(const float4*)(x + (size_t)grow * IN_DIM + kBase + lk);
            *(float4*)&xs[r][lk] = v;
        }
        // load W tile transposed: 128 cols x 64 k
        #pragma unroll
        for (int i = 0; i < 8; ++i) {
            int c = i * 16 + lr;
            float4 v = *(const float4*)(W + (size_t)c * IN_DIM + kBase + lk);
            wsT[lk + 0][c] = v.x;
            wsT[lk + 1][c] = v.y;
            wsT[lk + 2][c] = v.z;
            wsT[lk + 3][c] = v.w;
        }
        __syncthreads();

        #pragma unroll 8
        for (int k = 0; k < 64; ++k) {
            float4 wv = *(const float4*)&wsT[k][c0];
            #pragma unroll
            for (int i = 0; i < 8; ++i) {
                float a = xs[r0 + i][k];
                acc[i][0] += a * wv.x;
                acc[i][1] += a * wv.y;
                acc[i][2] += a * wv.z;
                acc[i][3] += a * wv.w;
            }
        }
        __syncthreads();
    }

    // epilogue: row L2 norms via LDS reduction (overlay on xs storage)
    float* red = &xs[0][0];  // red[r*33 + g], 64*33 floats fits in xs
    #pragma unroll
    for (int i = 0; i < 8; ++i) {
        float s = acc[i][0] * acc[i][0] + acc[i][1] * acc[i][1]
                + acc[i][2] * acc[i][2] + acc[i][3] * acc[i][3];
        red[(r0 + i) * 33 + cg] = s;
    }
    __syncthreads();
    if (t < 64) {
        float s = 0.f;
        #pragma unroll
        for (int g = 0; g < 32; ++g) s += red[t * 33 + g];
        red[t * 33 + 32] = SCALE / fmaxf(sqrtf(s), 1e-12f);
    }
    __syncthreads();
    #pragma unroll
    for (int i = 0; i < 8; ++i) {
        int grow = rowBase + r0 + i;
        if (grow < NNODES) {
            float scl = red[(r0 + i) * 33 + 32];
            float4 o = make_float4(acc[i][0] * scl, acc[i][1] * scl,
                                   acc[i][2] * scl, acc[i][3] * scl);
            *(float4*)(hn + (size_t)grow * OUT_DIM + c0) = o;
        }
    }
}

// ---------------- fused gather propagation ----------------
// one block (128 threads) per destination node; no atomics.
// outz[c] = (1-a) * dinv[c] * (sum_in dinv[r]*z[r] + dinv[c]*z[c]) + a*hn[c]

__global__ void __launch_bounds__(128) gather_kernel(
        const int* __restrict__ off, const int* __restrict__ csr_row,
        const float* __restrict__ dinv, const float* __restrict__ z,
        const float* __restrict__ hn, float* __restrict__ outz) {
    const int c = blockIdx.x;
    const int t = threadIdx.x;
    const int s = off[c];
    const int e = off[c + 1];
    const float dc = dinv[c];
    float acc = dc * z[(size_t)c * OUT_DIM + t];  // self-loop term
    for (int j = s; j < e; ++j) {
        int r = csr_row[j];           // uniform -> scalar load
        float w = dinv[r];            // uniform -> scalar load
        acc += w * z[(size_t)r * OUT_DIM + t];
    }
    outz[(size_t)c * OUT_DIM + t] =
        (1.0f - ALPHA) * (dc * acc) + ALPHA * hn[(size_t)c * OUT_DIM + t];
}

extern "C" void kernel_launch(void* const* d_in, const int* in_sizes, int n_in,
                              void* d_out, int out_size, void* d_ws, size_t ws_size,
                              hipStream_t stream) {
    const float* x  = (const float*)d_in[0];
    const int*   ei = (const int*)d_in[1];
    const float* W  = (const float*)d_in[2];
    const float* b  = (const float*)d_in[3];
    float* out = (float*)d_out;

    int E = in_sizes[1] / 2;
    const int* row = ei;       // sources
    const int* col = ei + E;   // targets

    // workspace layout
    float* dinv = (float*)d_ws;                        // 50048 floats (also deg)
    float* hn   = dinv + 50048;                        // [N,128]
    float* z1   = hn + (size_t)NNODES * OUT_DIM;       // [N,128]
    int*   cnt  = (int*)(z1 + (size_t)NNODES * OUT_DIM);
    int*   off  = cnt + 50048;                         // N+1 (50056 slots)
    int*   cur  = off + 50056;
    int*   part = cur + 50048;                         // 256
    int*   csr_row = part + 256;                       // E ints

    // degrees -> dinv, cnt
    deg_init_kernel<<<(NNODES + 255) / 256, 256, 0, stream>>>(dinv);
    deg_scatter_kernel<<<(E + 255) / 256, 256, 0, stream>>>(col, dinv, E);
    dinv_cnt_kernel<<<(NNODES + 255) / 256, 256, 0, stream>>>(dinv, cnt);

    // CSR build
    scan_pass1<<<NB_SCAN, 256, 0, stream>>>(cnt, part);
    scan_pass2<<<1, 256, 0, stream>>>(part);
    scan_pass3<<<NB_SCAN, 256, 0, stream>>>(cnt, part, off, cur, E);
    csr_fill_kernel<<<(E + 255) / 256, 256, 0, stream>>>(row, col, cur, csr_row, E);

    // h = normalize(x @ W.T + b) * SCALE   (fused)
    gemm_norm_kernel<<<(NNODES + 63) / 64, 256, 0, stream>>>(x, W, b, hn);

    // two propagation rounds, gather-based, fully fused
    gather_kernel<<<NNODES, 128, 0, stream>>>(off, csr_row, dinv, hn, hn, z1);
    gather_kernel<<<NNODES, 128, 0, stream>>>(off, csr_row, dinv, z1, hn, out);
}

// Round 3
// 320.666 us; speedup vs baseline: 9.1414x; 1.1849x over previous
//
#include <hip/hip_runtime.h>
#include <hip/hip_bf16.h>

#define NNODES 50000
#define IN_DIM 256
#define OUT_DIM 128
#define SCALE 1.8f
#define ALPHA 0.15f
#define NB_SCAN 196  // ceil(50000/256)

// ---------------- degree count ----------------

__global__ void zero_cnt_kernel(int* __restrict__ cnt) {
    int i = blockIdx.x * blockDim.x + threadIdx.x;
    if (i < NNODES) cnt[i] = 0;
}

__global__ void deg_scatter_kernel(const int* __restrict__ col, int* __restrict__ cnt, int E) {
    int e = blockIdx.x * blockDim.x + threadIdx.x;
    if (e < E) atomicAdd(&cnt[col[e]], 1);
}

// ---------------- exclusive scan (3-pass) over cnt -> off, cur; fused dinv/selfw ----------------

__global__ void scan_pass1(const int* __restrict__ cnt, int* __restrict__ part) {
    __shared__ int sd[256];
    int t = threadIdx.x;
    int i = blockIdx.x * 256 + t;
    sd[t] = (i < NNODES) ? cnt[i] : 0;
    __syncthreads();
    for (int s = 128; s > 0; s >>= 1) {
        if (t < s) sd[t] += sd[t + s];
        __syncthreads();
    }
    if (t == 0) part[blockIdx.x] = sd[0];
}

__global__ void scan_pass2(int* __restrict__ part) {
    __shared__ int s[256];
    int t = threadIdx.x;
    int v = (t < NB_SCAN) ? part[t] : 0;
    s[t] = v;
    __syncthreads();
    for (int o = 1; o < 256; o <<= 1) {
        int u = (t >= o) ? s[t - o] : 0;
        __syncthreads();
        s[t] += u;
        __syncthreads();
    }
    if (t < NB_SCAN) part[t] = (t == 0) ? 0 : s[t - 1];
}

__global__ void scan_pass3(const int* __restrict__ cnt, const int* __restrict__ part,
                           int* __restrict__ off, int* __restrict__ cur,
                           float* __restrict__ dinv, float* __restrict__ selfw, int E) {
    __shared__ int s[256];
    int t = threadIdx.x;
    int i = blockIdx.x * 256 + t;
    int v = (i < NNODES) ? cnt[i] : 0;
    s[t] = v;
    __syncthreads();
    for (int o = 1; o < 256; o <<= 1) {
        int u = (t >= o) ? s[t - o] : 0;
        __syncthreads();
        s[t] += u;
        __syncthreads();
    }
    int excl = part[blockIdx.x] + ((t == 0) ? 0 : s[t - 1]);
    if (i < NNODES) {
        off[i] = excl;
        cur[i] = excl;
        float d = rsqrtf((float)(v + 1));
        dinv[i] = d;
        selfw[i] = (1.0f - ALPHA) * d * d;
    }
    if (i == NNODES - 1) off[NNODES] = E;
}

__global__ void csr_fill_kernel(const int* __restrict__ row, const int* __restrict__ col,
                                const float* __restrict__ dinv, int* __restrict__ cur,
                                int* __restrict__ csr_row, float* __restrict__ csr_w, int E) {
    int e = blockIdx.x * blockDim.x + threadIdx.x;
    if (e < E) {
        int c = col[e];
        int r = row[e];
        int p = atomicAdd(&cur[c], 1);
        csr_row[p] = r;
        csr_w[p] = (1.0f - ALPHA) * dinv[r] * dinv[c];
    }
}

// ---------------- fused tiled GEMM + bias + L2-normalize ----------------
// BM=128, BN=128(all cols), BK=32; 256 threads; 8x8 register tile per thread.

__global__ void __launch_bounds__(256) gemm_norm_kernel(
        const float* __restrict__ x, const float* __restrict__ W,
        const float* __restrict__ b, float* __restrict__ hn) {
    __shared__ __align__(16) float xsT[32][132];  // [k][row], 528B row stride (16B mult)
    __shared__ __align__(16) float wsT[32][132];  // [k][col]

    const int t = threadIdx.x;
    const int r0 = 8 * (t >> 4);   // 0..120
    const int c0 = 8 * (t & 15);   // 0..120
    const int rowBase = blockIdx.x * 128;

    const int lr = t >> 3;         // 0..31
    const int lk = (t & 7) * 4;    // 0..28

    float acc[8][8];
    {
        const float4 bv0 = *(const float4*)(b + c0);
        const float4 bv1 = *(const float4*)(b + c0 + 4);
        #pragma unroll
        for (int i = 0; i < 8; ++i) {
            acc[i][0] = bv0.x; acc[i][1] = bv0.y; acc[i][2] = bv0.z; acc[i][3] = bv0.w;
            acc[i][4] = bv1.x; acc[i][5] = bv1.y; acc[i][6] = bv1.z; acc[i][7] = bv1.w;
        }
    }

    for (int kt = 0; kt < 8; ++kt) {
        const int kb = kt * 32;
        #pragma unroll
        for (int i = 0; i < 4; ++i) {
            int r = i * 32 + lr;  // 0..127
            int grow = rowBase + r;
            float4 v = make_float4(0.f, 0.f, 0.f, 0.f);
            if (grow < NNODES) v = *(const float4*)(x + (size_t)grow * IN_DIM + kb + lk);
            xsT[lk + 0][r] = v.x;
            xsT[lk + 1][r] = v.y;
            xsT[lk + 2][r] = v.z;
            xsT[lk + 3][r] = v.w;
            float4 wv = *(const float4*)(W + (size_t)r * IN_DIM + kb + lk);
            wsT[lk + 0][r] = wv.x;
            wsT[lk + 1][r] = wv.y;
            wsT[lk + 2][r] = wv.z;
            wsT[lk + 3][r] = wv.w;
        }
        __syncthreads();

        #pragma unroll 4
        for (int k = 0; k < 32; ++k) {
            float4 a0 = *(const float4*)&xsT[k][r0];
            float4 a1 = *(const float4*)&xsT[k][r0 + 4];
            float4 b0 = *(const float4*)&wsT[k][c0];
            float4 b1 = *(const float4*)&wsT[k][c0 + 4];
            float av[8] = {a0.x, a0.y, a0.z, a0.w, a1.x, a1.y, a1.z, a1.w};
            float bv[8] = {b0.x, b0.y, b0.z, b0.w, b1.x, b1.y, b1.z, b1.w};
            #pragma unroll
            for (int i = 0; i < 8; ++i)
                #pragma unroll
                for (int j = 0; j < 8; ++j)
                    acc[i][j] += av[i] * bv[j];
        }
        __syncthreads();
    }

    // epilogue: per-row L2 norm via LDS reduction (overlay on xsT)
    float* red = &xsT[0][0];  // red[row*17 + g], 128*17 = 2176 <= 4224
    const int cg = t & 15;
    #pragma unroll
    for (int i = 0; i < 8; ++i) {
        float s = 0.f;
        #pragma unroll
        for (int j = 0; j < 8; ++j) s += acc[i][j] * acc[i][j];
        red[(r0 + i) * 17 + cg] = s;
    }
    __syncthreads();
    if (t < 128) {
        float s = 0.f;
        #pragma unroll
        for (int g = 0; g < 16; ++g) s += red[t * 17 + g];
        red[t * 17 + 16] = SCALE / fmaxf(sqrtf(s), 1e-12f);
    }
    __syncthreads();
    #pragma unroll
    for (int i = 0; i < 8; ++i) {
        int grow = rowBase + r0 + i;
        if (grow < NNODES) {
            float scl = red[(r0 + i) * 17 + 16];
            float4 o0 = make_float4(acc[i][0] * scl, acc[i][1] * scl,
                                    acc[i][2] * scl, acc[i][3] * scl);
            float4 o1 = make_float4(acc[i][4] * scl, acc[i][5] * scl,
                                    acc[i][6] * scl, acc[i][7] * scl);
            *(float4*)(hn + (size_t)grow * OUT_DIM + c0) = o0;
            *(float4*)(hn + (size_t)grow * OUT_DIM + c0 + 4) = o1;
        }
    }
}

// ---------------- gather propagation: wave-per-node, shuffle-broadcast ----------------
// out[c] = sum_j csr_w[j]*z[r_j] + selfw[c]*z[c] + ALPHA*hn[c]

__global__ void __launch_bounds__(256) gather_kernel(
        const int* __restrict__ off, const int* __restrict__ csr_row,
        const float* __restrict__ csr_w, const float* __restrict__ selfw,
        const float* __restrict__ z, const float* __restrict__ hn,
        float* __restrict__ outz) {
    const int wv = threadIdx.x >> 6;
    const int lane = threadIdx.x & 63;
    const int c = blockIdx.x * 4 + wv;  // grid*4 == NNODES exactly
    const int s = off[c];
    const int e = off[c + 1];
    const float2* zp = (const float2*)z;

    float2 acc;
    {
        float sw = selfw[c];
        float2 zc = zp[(size_t)c * 64 + lane];
        acc.x = sw * zc.x;
        acc.y = sw * zc.y;
    }

    for (int base = s; base < e; base += 64) {
        int n = e - base;
        if (n > 64) n = 64;
        int idx = 0;
        float w = 0.f;
        if (lane < n) {
            idx = csr_row[base + lane];
            w = csr_w[base + lane];
        }
        int j = 0;
        for (; j + 4 <= n; j += 4) {
            int r0 = __shfl(idx, j + 0), r1 = __shfl(idx, j + 1);
            int r2 = __shfl(idx, j + 2), r3 = __shfl(idx, j + 3);
            float w0 = __shfl(w, j + 0), w1 = __shfl(w, j + 1);
            float w2 = __shfl(w, j + 2), w3 = __shfl(w, j + 3);
            float2 v0 = zp[(size_t)r0 * 64 + lane];
            float2 v1 = zp[(size_t)r1 * 64 + lane];
            float2 v2 = zp[(size_t)r2 * 64 + lane];
            float2 v3 = zp[(size_t)r3 * 64 + lane];
            acc.x += w0 * v0.x; acc.y += w0 * v0.y;
            acc.x += w1 * v1.x; acc.y += w1 * v1.y;
            acc.x += w2 * v2.x; acc.y += w2 * v2.y;
            acc.x += w3 * v3.x; acc.y += w3 * v3.y;
        }
        for (; j < n; ++j) {
            int r = __shfl(idx, j);
            float ww = __shfl(w, j);
            float2 v = zp[(size_t)r * 64 + lane];
            acc.x += ww * v.x;
            acc.y += ww * v.y;
        }
    }

    float2 h = ((const float2*)hn)[(size_t)c * 64 + lane];
    float2 o;
    o.x = acc.x + ALPHA * h.x;
    o.y = acc.y + ALPHA * h.y;
    ((float2*)outz)[(size_t)c * 64 + lane] = o;
}

extern "C" void kernel_launch(void* const* d_in, const int* in_sizes, int n_in,
                              void* d_out, int out_size, void* d_ws, size_t ws_size,
                              hipStream_t stream) {
    const float* x  = (const float*)d_in[0];
    const int*   ei = (const int*)d_in[1];
    const float* W  = (const float*)d_in[2];
    const float* b  = (const float*)d_in[3];
    float* out = (float*)d_out;

    int E = in_sizes[1] / 2;
    const int* row = ei;       // sources
    const int* col = ei + E;   // targets

    // workspace layout (floats/ints, generous 64-multiple offsets)
    float* dinv  = (float*)d_ws;                        // 50048
    float* selfw = dinv + 50048;                        // 50048
    float* hn    = selfw + 50048;                       // 6,400,000
    float* z1    = hn + (size_t)NNODES * OUT_DIM;       // 6,400,000
    int*   cnt   = (int*)(z1 + (size_t)NNODES * OUT_DIM);  // 50048
    int*   off   = cnt + 50048;                         // 50112 (N+1 used)
    int*   cur   = off + 50112;                         // 50048
    int*   part  = cur + 50048;                         // 256
    int*   csr_row = part + 256;                        // E
    float* csr_w   = (float*)(csr_row + ((E + 63) & ~63));  // E

    zero_cnt_kernel<<<(NNODES + 255) / 256, 256, 0, stream>>>(cnt);
    deg_scatter_kernel<<<(E + 255) / 256, 256, 0, stream>>>(col, cnt, E);

    scan_pass1<<<NB_SCAN, 256, 0, stream>>>(cnt, part);
    scan_pass2<<<1, 256, 0, stream>>>(part);
    scan_pass3<<<NB_SCAN, 256, 0, stream>>>(cnt, part, off, cur, dinv, selfw, E);
    csr_fill_kernel<<<(E + 255) / 256, 256, 0, stream>>>(row, col, dinv, cur, csr_row, csr_w, E);

    gemm_norm_kernel<<<(NNODES + 127) / 128, 256, 0, stream>>>(x, W, b, hn);

    gather_kernel<<<NNODES / 4, 256, 0, stream>>>(off, csr_row, csr_w, selfw, hn, hn, z1);
    gather_kernel<<<NNODES / 4, 256, 0, stream>>>(off, csr_row, csr_w, selfw, z1, hn, out);
}

// Round 4
// 282.448 us; speedup vs baseline: 10.3783x; 1.1353x over previous
//
#include <hip/hip_runtime.h>
#include <hip/hip_bf16.h>

#define NNODES 50000
#define IN_DIM 256
#define OUT_DIM 128
#define SCALE 1.8f
#define ALPHA 0.15f
#define NB_SCAN 196  // ceil(50000/256)

// ---------------- helpers: bf16 pack/unpack ----------------

__device__ __forceinline__ unsigned short f2bf_rne(float f) {
    unsigned int u = __float_as_uint(f);
    unsigned int r = u + 0x7fffu + ((u >> 16) & 1u);  // round-to-nearest-even
    return (unsigned short)(r >> 16);
}

__device__ __forceinline__ float2 bf2_to_f2(unsigned int p) {
    float2 f;
    f.x = __uint_as_float(p << 16);
    f.y = __uint_as_float(p & 0xffff0000u);
    return f;
}

__device__ __forceinline__ unsigned int f2_to_bf2(float x, float y) {
    return (unsigned int)f2bf_rne(x) | ((unsigned int)f2bf_rne(y) << 16);
}

// ---------------- degree count ----------------

__global__ void zero_cnt_kernel(int* __restrict__ cnt) {
    int i = blockIdx.x * blockDim.x + threadIdx.x;
    if (i < NNODES) cnt[i] = 0;
}

__global__ void deg_scatter_kernel(const int* __restrict__ col, int* __restrict__ cnt, int E) {
    int e = blockIdx.x * blockDim.x + threadIdx.x;
    if (e < E) atomicAdd(&cnt[col[e]], 1);
}

// ---------------- exclusive scan (3-pass) over cnt -> off, cur; fused dinv/selfw ----------------

__global__ void scan_pass1(const int* __restrict__ cnt, int* __restrict__ part) {
    __shared__ int sd[256];
    int t = threadIdx.x;
    int i = blockIdx.x * 256 + t;
    sd[t] = (i < NNODES) ? cnt[i] : 0;
    __syncthreads();
    for (int s = 128; s > 0; s >>= 1) {
        if (t < s) sd[t] += sd[t + s];
        __syncthreads();
    }
    if (t == 0) part[blockIdx.x] = sd[0];
}

__global__ void scan_pass2(int* __restrict__ part) {
    __shared__ int s[256];
    int t = threadIdx.x;
    int v = (t < NB_SCAN) ? part[t] : 0;
    s[t] = v;
    __syncthreads();
    for (int o = 1; o < 256; o <<= 1) {
        int u = (t >= o) ? s[t - o] : 0;
        __syncthreads();
        s[t] += u;
        __syncthreads();
    }
    if (t < NB_SCAN) part[t] = (t == 0) ? 0 : s[t - 1];
}

__global__ void scan_pass3(const int* __restrict__ cnt, const int* __restrict__ part,
                           int* __restrict__ off, int* __restrict__ cur,
                           float* __restrict__ dinv, float* __restrict__ selfw, int E) {
    __shared__ int s[256];
    int t = threadIdx.x;
    int i = blockIdx.x * 256 + t;
    int v = (i < NNODES) ? cnt[i] : 0;
    s[t] = v;
    __syncthreads();
    for (int o = 1; o < 256; o <<= 1) {
        int u = (t >= o) ? s[t - o] : 0;
        __syncthreads();
        s[t] += u;
        __syncthreads();
    }
    int excl = part[blockIdx.x] + ((t == 0) ? 0 : s[t - 1]);
    if (i < NNODES) {
        off[i] = excl;
        cur[i] = excl;
        float d = rsqrtf((float)(v + 1));
        dinv[i] = d;
        selfw[i] = (1.0f - ALPHA) * d * d;
    }
    if (i == NNODES - 1) off[NNODES] = E;
}

__global__ void csr_fill_kernel(const int* __restrict__ row, const int* __restrict__ col,
                                const float* __restrict__ dinv, int* __restrict__ cur,
                                int* __restrict__ csr_row, float* __restrict__ csr_w, int E) {
    int e = blockIdx.x * blockDim.x + threadIdx.x;
    if (e < E) {
        int c = col[e];
        int r = row[e];
        int p = atomicAdd(&cur[c], 1);
        csr_row[p] = r;
        csr_w[p] = (1.0f - ALPHA) * dinv[r] * dinv[c];
    }
}

// ---------------- fused tiled GEMM + bias + L2-normalize ----------------
// BM=64, BN=128(all cols), BK=32; 128 threads; 8x8 register tile per thread.
// 782 blocks, 25.6 KB LDS -> 6 blocks/CU co-resident (occupancy fix vs BM=128).
// Writes hn (fp32, for alpha-term) and zb (bf16, propagation state).

__global__ void __launch_bounds__(128) gemm_norm_kernel(
        const float* __restrict__ x, const float* __restrict__ W,
        const float* __restrict__ b, float* __restrict__ hn,
        unsigned int* __restrict__ zb) {
    __shared__ __align__(16) float xsT[32][68];   // [k][row]
    __shared__ __align__(16) float wsT[32][132];  // [k][col]

    const int t = threadIdx.x;          // 0..127
    const int r0 = 8 * (t >> 4);        // 0..56
    const int c0 = 8 * (t & 15);        // 0..120
    const int rowBase = blockIdx.x * 64;

    const int lr = t >> 3;              // 0..15
    const int lk = (t & 7) * 4;         // 0..28

    float acc[8][8];
    {
        const float4 bv0 = *(const float4*)(b + c0);
        const float4 bv1 = *(const float4*)(b + c0 + 4);
        #pragma unroll
        for (int i = 0; i < 8; ++i) {
            acc[i][0] = bv0.x; acc[i][1] = bv0.y; acc[i][2] = bv0.z; acc[i][3] = bv0.w;
            acc[i][4] = bv1.x; acc[i][5] = bv1.y; acc[i][6] = bv1.z; acc[i][7] = bv1.w;
        }
    }

    for (int kt = 0; kt < 8; ++kt) {
        const int kb = kt * 32;
        #pragma unroll
        for (int i = 0; i < 4; ++i) {
            int r = i * 16 + lr;  // 0..63
            int grow = rowBase + r;
            float4 v = make_float4(0.f, 0.f, 0.f, 0.f);
            if (grow < NNODES) v = *(const float4*)(x + (size_t)grow * IN_DIM + kb + lk);
            xsT[lk + 0][r] = v.x;
            xsT[lk + 1][r] = v.y;
            xsT[lk + 2][r] = v.z;
            xsT[lk + 3][r] = v.w;
        }
        #pragma unroll
        for (int i = 0; i < 8; ++i) {
            int c = i * 16 + lr;  // 0..127
            float4 wv = *(const float4*)(W + (size_t)c * IN_DIM + kb + lk);
            wsT[lk + 0][c] = wv.x;
            wsT[lk + 1][c] = wv.y;
            wsT[lk + 2][c] = wv.z;
            wsT[lk + 3][c] = wv.w;
        }
        __syncthreads();

        #pragma unroll 4
        for (int k = 0; k < 32; ++k) {
            float4 a0 = *(const float4*)&xsT[k][r0];
            float4 a1 = *(const float4*)&xsT[k][r0 + 4];
            float4 b0 = *(const float4*)&wsT[k][c0];
            float4 b1 = *(const float4*)&wsT[k][c0 + 4];
            float av[8] = {a0.x, a0.y, a0.z, a0.w, a1.x, a1.y, a1.z, a1.w};
            float bv[8] = {b0.x, b0.y, b0.z, b0.w, b1.x, b1.y, b1.z, b1.w};
            #pragma unroll
            for (int i = 0; i < 8; ++i)
                #pragma unroll
                for (int j = 0; j < 8; ++j)
                    acc[i][j] += av[i] * bv[j];
        }
        __syncthreads();
    }

    // epilogue: per-row L2 norm via LDS reduction (overlay on xsT: need 64*17=1088 <= 2176)
    float* red = &xsT[0][0];
    const int cg = t & 15;
    #pragma unroll
    for (int i = 0; i < 8; ++i) {
        float s = 0.f;
        #pragma unroll
        for (int j = 0; j < 8; ++j) s += acc[i][j] * acc[i][j];
        red[(r0 + i) * 17 + cg] = s;
    }
    __syncthreads();
    if (t < 64) {
        float s = 0.f;
        #pragma unroll
        for (int g = 0; g < 16; ++g) s += red[t * 17 + g];
        red[t * 17 + 16] = SCALE / fmaxf(sqrtf(s), 1e-12f);
    }
    __syncthreads();
    #pragma unroll
    for (int i = 0; i < 8; ++i) {
        int grow = rowBase + r0 + i;
        if (grow < NNODES) {
            float scl = red[(r0 + i) * 17 + 16];
            float o[8];
            #pragma unroll
            for (int j = 0; j < 8; ++j) o[j] = acc[i][j] * scl;
            *(float4*)(hn + (size_t)grow * OUT_DIM + c0)     = make_float4(o[0], o[1], o[2], o[3]);
            *(float4*)(hn + (size_t)grow * OUT_DIM + c0 + 4) = make_float4(o[4], o[5], o[6], o[7]);
            uint4 pz;
            pz.x = f2_to_bf2(o[0], o[1]);
            pz.y = f2_to_bf2(o[2], o[3]);
            pz.z = f2_to_bf2(o[4], o[5]);
            pz.w = f2_to_bf2(o[6], o[7]);
            *(uint4*)(zb + (size_t)grow * 64 + (c0 >> 1)) = pz;
        }
    }
}

// ---------------- gather propagation: wave-per-node, bf16 state ----------------
// out[c] = sum_j csr_w[j]*z[r_j] + selfw[c]*z[c] + ALPHA*hn[c]
// FINAL=0: write bf16 zout_b ; FINAL=1: write fp32 zout_f.

template <int FINAL>
__global__ void __launch_bounds__(256) gather_kernel(
        const int* __restrict__ off, const int* __restrict__ csr_row,
        const float* __restrict__ csr_w, const float* __restrict__ selfw,
        const unsigned int* __restrict__ zb, const float* __restrict__ hn,
        unsigned int* __restrict__ zout_b, float* __restrict__ zout_f) {
    const int wv = threadIdx.x >> 6;
    const int lane = threadIdx.x & 63;
    const int c = blockIdx.x * 4 + wv;  // grid*4 == NNODES exactly
    const int s = off[c];
    const int e = off[c + 1];

    float2 acc;
    {
        float sw = selfw[c];
        float2 zc = bf2_to_f2(zb[(size_t)c * 64 + lane]);
        acc.x = sw * zc.x;
        acc.y = sw * zc.y;
    }

    for (int base = s; base < e; base += 64) {
        int n = e - base;
        if (n > 64) n = 64;
        int idx = 0;
        float w = 0.f;
        if (lane < n) {
            idx = csr_row[base + lane];
            w = csr_w[base + lane];
        }
        int j = 0;
        for (; j + 4 <= n; j += 4) {
            int r0 = __shfl(idx, j + 0), r1 = __shfl(idx, j + 1);
            int r2 = __shfl(idx, j + 2), r3 = __shfl(idx, j + 3);
            float w0 = __shfl(w, j + 0), w1 = __shfl(w, j + 1);
            float w2 = __shfl(w, j + 2), w3 = __shfl(w, j + 3);
            unsigned int p0 = zb[(size_t)r0 * 64 + lane];
            unsigned int p1 = zb[(size_t)r1 * 64 + lane];
            unsigned int p2 = zb[(size_t)r2 * 64 + lane];
            unsigned int p3 = zb[(size_t)r3 * 64 + lane];
            float2 v0 = bf2_to_f2(p0), v1 = bf2_to_f2(p1);
            float2 v2 = bf2_to_f2(p2), v3 = bf2_to_f2(p3);
            acc.x += w0 * v0.x; acc.y += w0 * v0.y;
            acc.x += w1 * v1.x; acc.y += w1 * v1.y;
            acc.x += w2 * v2.x; acc.y += w2 * v2.y;
            acc.x += w3 * v3.x; acc.y += w3 * v3.y;
        }
        for (; j < n; ++j) {
            int r = __shfl(idx, j);
            float ww = __shfl(w, j);
            float2 v = bf2_to_f2(zb[(size_t)r * 64 + lane]);
            acc.x += ww * v.x;
            acc.y += ww * v.y;
        }
    }

    float2 h = ((const float2*)hn)[(size_t)c * 64 + lane];
    float ox = acc.x + ALPHA * h.x;
    float oy = acc.y + ALPHA * h.y;
    if (FINAL) {
        ((float2*)zout_f)[(size_t)c * 64 + lane] = make_float2(ox, oy);
    } else {
        zout_b[(size_t)c * 64 + lane] = f2_to_bf2(ox, oy);
    }
}

extern "C" void kernel_launch(void* const* d_in, const int* in_sizes, int n_in,
                              void* d_out, int out_size, void* d_ws, size_t ws_size,
                              hipStream_t stream) {
    const float* x  = (const float*)d_in[0];
    const int*   ei = (const int*)d_in[1];
    const float* W  = (const float*)d_in[2];
    const float* b  = (const float*)d_in[3];
    float* out = (float*)d_out;

    int E = in_sizes[1] / 2;
    const int* row = ei;       // sources
    const int* col = ei + E;   // targets

    // workspace layout
    float* dinv  = (float*)d_ws;                        // 50048
    float* selfw = dinv + 50048;                        // 50048
    float* hn    = selfw + 50048;                       // 6,400,000 fp32
    unsigned int* zb  = (unsigned int*)(hn + (size_t)NNODES * OUT_DIM);  // 3,200,000 u32 (bf16x2)
    unsigned int* z1b = zb + (size_t)NNODES * 64;                        // 3,200,000 u32
    int*   cnt   = (int*)(z1b + (size_t)NNODES * 64);   // 50048
    int*   off   = cnt + 50048;                         // 50112 (N+1 used)
    int*   cur   = off + 50112;                         // 50048
    int*   part  = cur + 50048;                         // 256
    int*   csr_row = part + 256;                        // E
    float* csr_w   = (float*)(csr_row + ((E + 63) & ~63));  // E

    zero_cnt_kernel<<<(NNODES + 255) / 256, 256, 0, stream>>>(cnt);
    deg_scatter_kernel<<<(E + 255) / 256, 256, 0, stream>>>(col, cnt, E);

    scan_pass1<<<NB_SCAN, 256, 0, stream>>>(cnt, part);
    scan_pass2<<<1, 256, 0, stream>>>(part);
    scan_pass3<<<NB_SCAN, 256, 0, stream>>>(cnt, part, off, cur, dinv, selfw, E);
    csr_fill_kernel<<<(E + 255) / 256, 256, 0, stream>>>(row, col, dinv, cur, csr_row, csr_w, E);

    gemm_norm_kernel<<<(NNODES + 63) / 64, 128, 0, stream>>>(x, W, b, hn, zb);

    gather_kernel<0><<<NNODES / 4, 256, 0, stream>>>(off, csr_row, csr_w, selfw, zb, hn, z1b, nullptr);
    gather_kernel<1><<<NNODES / 4, 256, 0, stream>>>(off, csr_row, csr_w, selfw, z1b, hn, nullptr, out);
}